// Round 22
// baseline (108.350 us; speedup 1.0000x reference)
//
#include <hip/hip_runtime.h>

#define NN 4096
#define IN_DIM 256
#define HID 64
#define HEADS 8

typedef __attribute__((ext_vector_type(4))) float f32x4;
typedef __attribute__((ext_vector_type(8))) short s16x8;
typedef unsigned short u16;
typedef unsigned long long u64;

__device__ inline u16 f2bf(float f) {
  union { float f; unsigned u; } v; v.f = f;
  unsigned r = (v.u + 0x7FFFu + ((v.u >> 16) & 1u)) >> 16;
  return (u16)r;
}
__device__ inline float bf2f(u16 b) {
  union { unsigned u; float f; } v; v.u = ((unsigned)b) << 16;
  return v.f;
}
__device__ __forceinline__ unsigned cvt_pk_bf16(float a, float b) {
  unsigned r;
  asm("v_cvt_pk_bf16_f32 %0, %1, %2" : "=v"(r) : "v"(a), "v"(b));
  return r;  // lo = bf16(a), hi = bf16(b)
}
// monotone float->uint encoding for atomicMax (0 is identity: encf(finite)>0)
__device__ inline unsigned encf(float f) {
  unsigned u = __float_as_uint(f);
  return (u & 0x80000000u) ? ~u : (u | 0x80000000u);
}
__device__ inline float decf(unsigned k) {
  return (k & 0x80000000u) ? __uint_as_float(k & 0x7FFFFFFFu) : __uint_as_float(~k);
}

// ---------------------------------------------------------------------------
// Kernel 0: pack adjacency -> bitmask [4096 rows][64 u64 words].
// ---------------------------------------------------------------------------
__global__ __launch_bounds__(256) void gat_pack(
    const void* __restrict__ adj, u64* __restrict__ bits)
{
  __shared__ int smode;
  const int t = threadIdx.x;
  if (t < 64) {
    const unsigned char* a8 = (const unsigned char*)adj;
    const int* a32 = (const int*)adj;
    size_t i8 = (size_t)(4 * t + 1) * 4097;       // diag byte if u8
    int p8 = a8[i8] != 0;
    size_t k = (size_t)(2 * t + 1);               // odd
    int p32 = a32[k * 4097] != 0;                 // diag elem if i32
    int p64 = a32[2 * k * 4097] != 0;             // low word of diag if i64
    int ok8 = __all(p8), ok32 = __all(p32), ok64 = __all(p64);
    if (t == 0) smode = ok8 ? 0 : (ok32 ? 1 : (ok64 ? 2 : 1));
  }
  __syncthreads();
  const int mode = smode;

  const int lane = t & 63;
  const int wave = (blockIdx.x * blockDim.x + t) >> 6;
  const int nwaves = (gridDim.x * blockDim.x) >> 6;
  const size_t nwords = (size_t)NN * NN / 64;

  for (size_t w = wave; w < nwords; w += nwaves) {
    size_t e = w * 64 + lane;
    int on;
    if (mode == 1)      on = ((const int*)adj)[e] != 0;
    else if (mode == 0) on = ((const unsigned char*)adj)[e] != 0;
    else                on = ((const long long*)adj)[e] != 0;
    u64 b = __ballot(on);
    if (lane == 0) bits[w] = b;
  }
}

// ---------------------------------------------------------------------------
// Kernel 1: H = x @ W^T (inline bf16 hi/lo split), TILED bf16 out
// Hbt2[h][jt][f][j_in]; epilogue computes src scores, per-head dst max,
// and the FACTORIZED softmax tables F1 = exp2(d*L2E), F2 = exp2(0.2d*L2E)
// (replaces raw dst scores; flash then needs no transcendentals).
// ---------------------------------------------------------------------------
__global__ __launch_bounds__(256) void gat_gemm1(
    const float* __restrict__ x, const float* __restrict__ W,
    const float* __restrict__ a_src, const float* __restrict__ a_dst,
    u16* __restrict__ Hbt, float* __restrict__ s_srcT,
    float* __restrict__ F1, float* __restrict__ F2,
    unsigned* __restrict__ Mh_enc)
{
  __shared__ u16 xhi[64 * 72], xlo[64 * 72], whi[64 * 72], wlo[64 * 72];
  const int nb = blockIdx.x;
  const int ob = blockIdx.y;
  const int t = threadIdx.x;
  const int lane = t & 63, wid = t >> 6;
  const int wr = wid >> 1, wc = wid & 1;
  const int g = lane >> 4;

  f32x4 acc[2][2] = {};

  const int sn = t >> 2;
  const int skc = (t & 3) * 16;

  for (int kb = 0; kb < 4; ++kb) {
    const float* xr = x + (size_t)(nb * 64 + sn) * IN_DIM + kb * 64 + skc;
    const float* wr_p = W + (size_t)(ob * 64 + sn) * IN_DIM + kb * 64 + skc;
#pragma unroll
    for (int c = 0; c < 4; ++c) {
      float4 xv = ((const float4*)xr)[c];
      float4 wv = ((const float4*)wr_p)[c];
      float xf[4] = {xv.x, xv.y, xv.z, xv.w};
      float wf[4] = {wv.x, wv.y, wv.z, wv.w};
      u16 xh[4], xl[4], wh[4], wl[4];
#pragma unroll
      for (int e = 0; e < 4; ++e) {
        xh[e] = f2bf(xf[e]); xl[e] = f2bf(xf[e] - bf2f(xh[e]));
        wh[e] = f2bf(wf[e]); wl[e] = f2bf(wf[e] - bf2f(wh[e]));
      }
      int base = sn * 72 + skc + c * 4;
      *(ushort4*)(xhi + base) = make_ushort4(xh[0], xh[1], xh[2], xh[3]);
      *(ushort4*)(xlo + base) = make_ushort4(xl[0], xl[1], xl[2], xl[3]);
      *(ushort4*)(whi + base) = make_ushort4(wh[0], wh[1], wh[2], wh[3]);
      *(ushort4*)(wlo + base) = make_ushort4(wl[0], wl[1], wl[2], wl[3]);
    }
    __syncthreads();
#pragma unroll
    for (int ks = 0; ks < 2; ++ks) {
      const int k0 = ks * 32 + g * 8;
      s16x8 ah[2], al[2], bh[2], bl[2];
#pragma unroll
      for (int nf = 0; nf < 2; ++nf) {
        int row = wr * 32 + nf * 16 + (lane & 15);
        ah[nf] = *(const s16x8*)(xhi + row * 72 + k0);
        al[nf] = *(const s16x8*)(xlo + row * 72 + k0);
      }
#pragma unroll
      for (int of = 0; of < 2; ++of) {
        int row = wc * 32 + of * 16 + (lane & 15);
        bh[of] = *(const s16x8*)(whi + row * 72 + k0);
        bl[of] = *(const s16x8*)(wlo + row * 72 + k0);
      }
#pragma unroll
      for (int nf = 0; nf < 2; ++nf)
#pragma unroll
        for (int of = 0; of < 2; ++of) {
          acc[nf][of] = __builtin_amdgcn_mfma_f32_16x16x32_bf16(ah[nf], bh[of], acc[nf][of], 0, 0, 0);
          acc[nf][of] = __builtin_amdgcn_mfma_f32_16x16x32_bf16(ah[nf], bl[of], acc[nf][of], 0, 0, 0);
          acc[nf][of] = __builtin_amdgcn_mfma_f32_16x16x32_bf16(al[nf], bh[of], acc[nf][of], 0, 0, 0);
        }
    }
    __syncthreads();
  }

  u16* Ct = xhi;  // [64 o][72 n]
#pragma unroll
  for (int nf = 0; nf < 2; ++nf)
#pragma unroll
    for (int of = 0; of < 2; ++of)
#pragma unroll
      for (int r = 0; r < 4; ++r) {
        int nloc = wr * 32 + nf * 16 + g * 4 + r;
        int oloc = wc * 32 + of * 16 + (lane & 15);
        Ct[oloc * 72 + nloc] = f2bf(acc[nf][of][r]);
      }

  {
    const float* asp = a_src + ob * 64;
    const float* adp = a_dst + ob * 64;
    float as0 = asp[wc * 32 + (lane & 15)], as1 = asp[wc * 32 + 16 + (lane & 15)];
    float ad0 = adp[wc * 32 + (lane & 15)], ad1 = adp[wc * 32 + 16 + (lane & 15)];
    float* sred = (float*)wlo;
#pragma unroll
    for (int nf = 0; nf < 2; ++nf)
#pragma unroll
      for (int r = 0; r < 4; ++r) {
        float vs = acc[nf][0][r] * as0 + acc[nf][1][r] * as1;
        float vd = acc[nf][0][r] * ad0 + acc[nf][1][r] * ad1;
#pragma unroll
        for (int m = 1; m < 16; m <<= 1) { vs += __shfl_xor(vs, m); vd += __shfl_xor(vd, m); }
        if ((lane & 15) == 0) {
          int node = wr * 32 + nf * 16 + g * 4 + r;
          sred[wc * 64 + node] = vs;
          sred[128 + wc * 64 + node] = vd;
        }
      }
  }
  __syncthreads();
  {
    int o = t >> 2, nc = (t & 3) * 16;
    u16* dst = Hbt + ((size_t)(ob * 64 + nb) * 64 + o) * 64 + nc;
#pragma unroll
    for (int c = 0; c < 2; ++c) {
      s16x8 v = *(const s16x8*)(Ct + o * 72 + nc + c * 8);
      *(s16x8*)(dst + c * 8) = v;
    }
  }
  if (t < 64) {
    const float* sred = (const float*)wlo;
    float vssum = sred[t] + sred[64 + t];
    float vdsum = sred[128 + t] + sred[192 + t];
    const float L2E = 1.44269504f;
    s_srcT[(size_t)ob * NN + nb * 64 + t] = vssum;
    F1[(size_t)ob * NN + nb * 64 + t] = __builtin_amdgcn_exp2f(vdsum * L2E);
    F2[(size_t)ob * NN + nb * 64 + t] = __builtin_amdgcn_exp2f(0.2f * vdsum * L2E);
    float m = vdsum;
#pragma unroll
    for (int s = 1; s < 64; s <<= 1) m = fmaxf(m, __shfl_xor(m, s));
    if (t == 0) atomicMax(Mh_enc + ob, encf(m));
  }
}

// ---------------------------------------------------------------------------
// Kernel 2: flash-GAT, TRANS-FREE inner loop. exp factorized through the
// leaky-relu branches:  z>0: p = a1*F1_j ; z<=0: p = a2*F2_j, with the
// branch test done as F1_j > th (monotone equivalent of s_i + d_j > 0).
// Per element: cmp + 2 cndmask + mul + mask-cndmask; ZERO v_exp in the loop.
// Shape: R17-proven (block = head x 64 i-rows, 512 thr, grid 512, dbuf
// staging 1 barrier/tile, l-sum via all-ones MFMA, fixed-m softmax).
// ---------------------------------------------------------------------------
__global__ __launch_bounds__(512, 4) void gat_flash(
    const u64* __restrict__ bits, const u16* __restrict__ Hbt,
    const float* __restrict__ s_srcT, const float* __restrict__ F1,
    const float* __restrict__ F2, const unsigned* __restrict__ Mh_enc,
    float* __restrict__ pout)
{
  __shared__ char shmem[32768];   // u16 Ast[2 jh][2 dbuf][4096] | float accst[4][16][66]
  __shared__ float Lbuf[8][16];
  u16* Ast = (u16*)shmem;

  const int t = threadIdx.x, lane = t & 63, wid = t >> 6;
  const int ws4 = wid & 3, jh = wid >> 2;
  const int bid = blockIdx.x;
  const int h = bid & 7, iblk = bid >> 3;
  const int i_loc = lane & 15, g = lane >> 4, j0 = g * 8;
  const int irow = iblk * 64 + ws4 * 16 + i_loc;

  const float L2E = 1.44269504f;
  const float s_i = s_srcT[(size_t)h * NN + irow];
  float m_i = s_i + decf(Mh_enc[h]);
  m_i = fmaxf(m_i, 0.2f * m_i);                 // lrelu(s_i + M_h) >= all z
  const float mL = m_i * L2E;
  // factorized per-lane constants (only transcendentals in this kernel)
  const float a1 = __builtin_amdgcn_exp2f(__builtin_fmaf(s_i, L2E, -mL));
  const float a2 = __builtin_amdgcn_exp2f(__builtin_fmaf(0.2f * s_i, L2E, -mL));
  const float th = __builtin_amdgcn_exp2f(-s_i * L2E);

  const u16* tile0 = Hbt + (size_t)h * 64 * 4096;

  const int lt = t & 255;
  const int r0 = lt >> 3, colE = (lt & 7) * 8;
  const int jtb = jh * 32;
  const u16* gsrc0 = tile0 + (size_t)jtb * 4096 + r0 * 64 + (colE ^ ((r0 & 7) << 3));
  const u16* gsrc1 = tile0 + (size_t)jtb * 4096 + (32 + r0) * 64 + (colE ^ ((r0 & 7) << 3));
  const u64* brow = bits + (size_t)irow * 64 + jtb;
  const float* p1 = F1 + (size_t)h * NN + jtb * 64 + j0;
  const float* p2 = F2 + (size_t)h * NN + jtb * 64 + j0;

  u16* sdstA = Ast + jh * 8192;
  u16* sdstB = sdstA + 4096;
  const char* lbaseA = (const char*)sdstA;
  const char* lbaseB = (const char*)sdstB;
  const int swz = (i_loc & 7) << 4;
  const int ofA0 = (g * 16) ^ swz, ofA1 = ((g * 16) + 64) ^ swz;

  s16x8 ones;
#pragma unroll
  for (int e = 0; e < 8; ++e) ones[e] = (short)0x3F80;

  f32x4 acc[4] = {};
  f32x4 acc_l = {0.f, 0.f, 0.f, 0.f};

#define QUAD(V1, V2, MBITS, SH, PW0, PW1) do {                        \
    bool c0 = V1[0] > th, c1 = V1[1] > th;                            \
    bool c2 = V1[2] > th, c3 = V1[3] > th;                            \
    float e0 = (c0 ? a1 : a2) * (c0 ? V1[0] : V2[0]);                 \
    float e1 = (c1 ? a1 : a2) * (c1 ? V1[1] : V2[1]);                 \
    float e2 = (c2 ? a1 : a2) * (c2 ? V1[2] : V2[2]);                 \
    float e3 = (c3 ? a1 : a2) * (c3 ? V1[3] : V2[3]);                 \
    e0 = ((MBITS >> (SH + 0)) & 1u) ? e0 : 0.f;                       \
    e1 = ((MBITS >> (SH + 1)) & 1u) ? e1 : 0.f;                       \
    e2 = ((MBITS >> (SH + 2)) & 1u) ? e2 : 0.f;                       \
    e3 = ((MBITS >> (SH + 3)) & 1u) ? e3 : 0.f;                       \
    PW0 = cvt_pk_bf16(e0, e1); PW1 = cvt_pk_bf16(e2, e3);             \
  } while (0)

#define TILE_BODY(SDST, LBASE) do {                                   \
    *(s16x8*)((SDST) + lt * 8) = sv0;                                 \
    *(s16x8*)((SDST) + 2048 + lt * 8) = sv1;                          \
    gsrc0 += 4096; gsrc1 += 4096;                                     \
    sv0 = *(const s16x8*)(gsrc0);                                     \
    sv1 = *(const s16x8*)(gsrc1);                                     \
    const u64 am_ = *brow++;                                          \
    f32x4 v1a = *(const f32x4*)(p1);                                  \
    f32x4 v1b = *(const f32x4*)(p1 + 4);                              \
    f32x4 v1c = *(const f32x4*)(p1 + 32);                             \
    f32x4 v1d = *(const f32x4*)(p1 + 36);                             \
    f32x4 v2a = *(const f32x4*)(p2);                                  \
    f32x4 v2b = *(const f32x4*)(p2 + 4);                              \
    f32x4 v2c = *(const f32x4*)(p2 + 32);                             \
    f32x4 v2d = *(const f32x4*)(p2 + 36);                             \
    p1 += 64; p2 += 64;                                               \
    const unsigned amlo = (unsigned)(am_ >> j0);                      \
    const unsigned amhi = (unsigned)(am_ >> (32 + j0));               \
    union { unsigned w_[4]; s16x8 v_; } P0, P1;                       \
    QUAD(v1a, v2a, amlo, 0, P0.w_[0], P0.w_[1]);                      \
    QUAD(v1b, v2b, amlo, 4, P0.w_[2], P0.w_[3]);                      \
    QUAD(v1c, v2c, amhi, 0, P1.w_[0], P1.w_[1]);                      \
    QUAD(v1d, v2d, amhi, 4, P1.w_[2], P1.w_[3]);                      \
    __syncthreads();                                                  \
    _Pragma("unroll")                                                 \
    for (int fb = 0; fb < 4; ++fb) {                                  \
      const int rowb = (fb * 16 + i_loc) * 128;                       \
      s16x8 A0 = *(const s16x8*)((LBASE) + rowb + ofA0);              \
      s16x8 A1 = *(const s16x8*)((LBASE) + rowb + ofA1);              \
      acc[fb] = __builtin_amdgcn_mfma_f32_16x16x32_bf16(A0, P0.v_, acc[fb], 0, 0, 0); \
      acc[fb] = __builtin_amdgcn_mfma_f32_16x16x32_bf16(A1, P1.v_, acc[fb], 0, 0, 0); \
    }                                                                 \
    acc_l = __builtin_amdgcn_mfma_f32_16x16x32_bf16(ones, P0.v_, acc_l, 0, 0, 0); \
    acc_l = __builtin_amdgcn_mfma_f32_16x16x32_bf16(ones, P1.v_, acc_l, 0, 0, 0); \
  } while (0)

  s16x8 sv0 = *(const s16x8*)(gsrc0);
  s16x8 sv1 = *(const s16x8*)(gsrc1);

  for (int it = 0; it < 16; ++it) {
    TILE_BODY(sdstA, lbaseA);
    TILE_BODY(sdstB, lbaseB);
  }
#undef QUAD
#undef TILE_BODY

  // every lane holds l for its own row in acc_l[0] (MFMA C col = lane&15)
  float l_run = acc_l[0];
  if (lane < 16) Lbuf[wid][i_loc] = l_run;

  __syncthreads();     // final tile's ds_reads retired; Lbuf visible
  float* accst = (float*)shmem;  // [4][16][66] = jh==1's 4 i-subwaves
  if (jh == 1) {
    float* ab = accst + (ws4 * 16 + i_loc) * 66;
#pragma unroll
    for (int fb = 0; fb < 4; ++fb)
      *(f32x4*)(ab + fb * 16 + g * 4) = acc[fb];
  }
  __syncthreads();
  if (jh == 0) {
    const float invL = 1.f / (l_run + Lbuf[4 + ws4][i_loc]);
    float* ob = pout + ((size_t)h * NN + irow) * 64;
#pragma unroll
    for (int fb = 0; fb < 4; ++fb) {
      f32x4 v = acc[fb] +
          *(const f32x4*)(accst + (ws4 * 16 + i_loc) * 66 + fb * 16 + g * 4);
      *(f32x4*)(ob + fb * 16 + g * 4) = v * invL;
    }
  }
}

// ---------------------------------------------------------------------------
// Kernel 3: combine 8 per-head partials, apply 1/8 head-mean.
// ---------------------------------------------------------------------------
__global__ __launch_bounds__(256) void gat_combine(
    const float* __restrict__ pout, float* __restrict__ out)
{
  size_t e = (size_t)blockIdx.x * 256 + threadIdx.x;   // f32x4 index
  f32x4 s = {0.f, 0.f, 0.f, 0.f};
#pragma unroll
  for (int h = 0; h < 8; ++h)
    s += ((const f32x4*)pout)[(size_t)h * (NN * 16) + e];
  ((f32x4*)out)[e] = s * 0.125f;
}

extern "C" void kernel_launch(void* const* d_in, const int* in_sizes, int n_in,
                              void* d_out, int out_size, void* d_ws, size_t ws_size,
                              hipStream_t stream)
{
  const float* x = (const float*)d_in[0];
  const void* adj = d_in[1];
  const float* W = (const float*)d_in[2];
  const float* a_src = (const float*)d_in[3];
  const float* a_dst = (const float*)d_in[4];
  float* out = (float*)d_out;

  char* ws = (char*)d_ws;
  float* pout = (float*)ws;                                 // 8 MB [8][NN][64]
  u16* Hbt = (u16*)(ws + 8 * 1024 * 1024);                  // 4 MB [8][64][64][64]
  float* s_srcT = (float*)(ws + 12 * 1024 * 1024);          // 128 KB [8][4096]
  float* F1 = (float*)(ws + 12 * 1024 * 1024 + 128 * 1024); // 128 KB
  float* F2 = (float*)(ws + 12 * 1024 * 1024 + 256 * 1024); // 128 KB
  unsigned* Mh_enc = (unsigned*)(ws + 12 * 1024 * 1024 + 400 * 1024); // 32 B
  u64* bits = (u64*)(ws + 12 * 1024 * 1024 + 512 * 1024);   // 2 MB

  hipMemsetAsync(Mh_enc, 0, 32, stream);
  gat_pack<<<2048, 256, 0, stream>>>(adj, bits);
  gat_gemm1<<<dim3(64, 8), 256, 0, stream>>>(x, W, a_src, a_dst, Hbt,
                                             s_srcT, F1, F2, Mh_enc);
  gat_flash<<<512, 512, 0, stream>>>(bits, Hbt, s_srcT, F1, F2, Mh_enc, pout);
  gat_combine<<<256, 256, 0, stream>>>(pout, out);
}

// Round 23
// 90.124 us; speedup vs baseline: 1.2022x; 1.2022x over previous
//
#include <hip/hip_runtime.h>

#define NN 4096
#define IN_DIM 256
#define HID 64
#define HEADS 8

typedef __attribute__((ext_vector_type(4))) float f32x4;
typedef __attribute__((ext_vector_type(8))) short s16x8;
typedef unsigned short u16;
typedef unsigned long long u64;

__device__ inline u16 f2bf(float f) {
  union { float f; unsigned u; } v; v.f = f;
  unsigned r = (v.u + 0x7FFFu + ((v.u >> 16) & 1u)) >> 16;
  return (u16)r;
}
__device__ inline float bf2f(u16 b) {
  union { unsigned u; float f; } v; v.u = ((unsigned)b) << 16;
  return v.f;
}
__device__ __forceinline__ unsigned cvt_pk_bf16(float a, float b) {
  unsigned r;
  asm("v_cvt_pk_bf16_f32 %0, %1, %2" : "=v"(r) : "v"(a), "v"(b));
  return r;  // lo = bf16(a), hi = bf16(b)
}

// ---------------------------------------------------------------------------
// Kernel 0: pack adjacency into bitmask [4096 rows][64 u64 words].
// Element width (u8/i32/i64) detected inline by each block's first wave.
// ---------------------------------------------------------------------------
__global__ __launch_bounds__(256) void gat_pack(
    const void* __restrict__ adj, u64* __restrict__ bits)
{
  __shared__ int smode;
  const int t = threadIdx.x;
  if (t < 64) {
    const unsigned char* a8 = (const unsigned char*)adj;
    const int* a32 = (const int*)adj;
    size_t i8 = (size_t)(4 * t + 1) * 4097;       // diag byte if u8
    int p8 = a8[i8] != 0;
    size_t k = (size_t)(2 * t + 1);               // odd
    int p32 = a32[k * 4097] != 0;                 // diag elem if i32
    int p64 = a32[2 * k * 4097] != 0;             // low word of diag if i64
    int ok8 = __all(p8), ok32 = __all(p32), ok64 = __all(p64);
    if (t == 0) smode = ok8 ? 0 : (ok32 ? 1 : (ok64 ? 2 : 1));
  }
  __syncthreads();
  const int mode = smode;

  const int lane = t & 63;
  const int wave = (blockIdx.x * blockDim.x + t) >> 6;
  const int nwaves = (gridDim.x * blockDim.x) >> 6;
  const size_t nwords = (size_t)NN * NN / 64;

  for (size_t w = wave; w < nwords; w += nwaves) {
    size_t e = w * 64 + lane;
    int on;
    if (mode == 1)      on = ((const int*)adj)[e] != 0;
    else if (mode == 0) on = ((const unsigned char*)adj)[e] != 0;
    else                on = ((const long long*)adj)[e] != 0;
    u64 b = __ballot(on);
    if (lane == 0) bits[w] = b;
  }
}

// ---------------------------------------------------------------------------
// Kernel 1: H = x @ W^T, TILED bf16 out Hbt2[h][jt][f][j_in], PLUS src/dst
// scores computed in the epilogue -> no f32 H buffer, no scores kernel.
// ---------------------------------------------------------------------------
__global__ __launch_bounds__(256) void gat_gemm1(
    const float* __restrict__ x, const float* __restrict__ W,
    const float* __restrict__ a_src, const float* __restrict__ a_dst,
    u16* __restrict__ Hbt, float* __restrict__ s_srcT,
    float* __restrict__ s_dstT)
{
  __shared__ u16 xhi[64 * 72], xlo[64 * 72], whi[64 * 72], wlo[64 * 72];
  const int nb = blockIdx.x;   // node block (rows) == j-tile index
  const int ob = blockIdx.y;   // out block  (cols) == head
  const int t = threadIdx.x;
  const int lane = t & 63, wid = t >> 6;
  const int wr = wid >> 1, wc = wid & 1;
  const int g = lane >> 4;

  f32x4 acc[2][2] = {};

  const int sn = t >> 2;          // staging row 0..63
  const int skc = (t & 3) * 16;   // staging k offset within 64-chunk

  for (int kb = 0; kb < 4; ++kb) {
    const float* xr = x + (size_t)(nb * 64 + sn) * IN_DIM + kb * 64 + skc;
    const float* wr_p = W + (size_t)(ob * 64 + sn) * IN_DIM + kb * 64 + skc;
#pragma unroll
    for (int c = 0; c < 4; ++c) {
      float4 xv = ((const float4*)xr)[c];
      float4 wv = ((const float4*)wr_p)[c];
      float xf[4] = {xv.x, xv.y, xv.z, xv.w};
      float wf[4] = {wv.x, wv.y, wv.z, wv.w};
      u16 xh[4], xl[4], wh[4], wl[4];
#pragma unroll
      for (int e = 0; e < 4; ++e) {
        xh[e] = f2bf(xf[e]); xl[e] = f2bf(xf[e] - bf2f(xh[e]));
        wh[e] = f2bf(wf[e]); wl[e] = f2bf(wf[e] - bf2f(wh[e]));
      }
      int base = sn * 72 + skc + c * 4;
      *(ushort4*)(xhi + base) = make_ushort4(xh[0], xh[1], xh[2], xh[3]);
      *(ushort4*)(xlo + base) = make_ushort4(xl[0], xl[1], xl[2], xl[3]);
      *(ushort4*)(whi + base) = make_ushort4(wh[0], wh[1], wh[2], wh[3]);
      *(ushort4*)(wlo + base) = make_ushort4(wl[0], wl[1], wl[2], wl[3]);
    }
    __syncthreads();
#pragma unroll
    for (int ks = 0; ks < 2; ++ks) {
      const int k0 = ks * 32 + g * 8;
      s16x8 ah[2], al[2], bh[2], bl[2];
#pragma unroll
      for (int nf = 0; nf < 2; ++nf) {
        int row = wr * 32 + nf * 16 + (lane & 15);
        ah[nf] = *(const s16x8*)(xhi + row * 72 + k0);
        al[nf] = *(const s16x8*)(xlo + row * 72 + k0);
      }
#pragma unroll
      for (int of = 0; of < 2; ++of) {
        int row = wc * 32 + of * 16 + (lane & 15);
        bh[of] = *(const s16x8*)(whi + row * 72 + k0);
        bl[of] = *(const s16x8*)(wlo + row * 72 + k0);
      }
#pragma unroll
      for (int nf = 0; nf < 2; ++nf)
#pragma unroll
        for (int of = 0; of < 2; ++of) {
          acc[nf][of] = __builtin_amdgcn_mfma_f32_16x16x32_bf16(ah[nf], bh[of], acc[nf][of], 0, 0, 0);
          acc[nf][of] = __builtin_amdgcn_mfma_f32_16x16x32_bf16(ah[nf], bl[of], acc[nf][of], 0, 0, 0);
          acc[nf][of] = __builtin_amdgcn_mfma_f32_16x16x32_bf16(al[nf], bh[of], acc[nf][of], 0, 0, 0);
        }
    }
    __syncthreads();
  }

  // ---- epilogue ----
  u16* Ct = xhi;  // [64 o][72 n]
#pragma unroll
  for (int nf = 0; nf < 2; ++nf)
#pragma unroll
    for (int of = 0; of < 2; ++of)
#pragma unroll
      for (int r = 0; r < 4; ++r) {
        int nloc = wr * 32 + nf * 16 + g * 4 + r;
        int oloc = wc * 32 + of * 16 + (lane & 15);
        Ct[oloc * 72 + nloc] = f2bf(acc[nf][of][r]);
      }

  {
    const float* asp = a_src + ob * 64;
    const float* adp = a_dst + ob * 64;
    float as0 = asp[wc * 32 + (lane & 15)], as1 = asp[wc * 32 + 16 + (lane & 15)];
    float ad0 = adp[wc * 32 + (lane & 15)], ad1 = adp[wc * 32 + 16 + (lane & 15)];
    float* sred = (float*)wlo;
#pragma unroll
    for (int nf = 0; nf < 2; ++nf)
#pragma unroll
      for (int r = 0; r < 4; ++r) {
        float vs = acc[nf][0][r] * as0 + acc[nf][1][r] * as1;
        float vd = acc[nf][0][r] * ad0 + acc[nf][1][r] * ad1;
#pragma unroll
        for (int m = 1; m < 16; m <<= 1) { vs += __shfl_xor(vs, m); vd += __shfl_xor(vd, m); }
        if ((lane & 15) == 0) {
          int node = wr * 32 + nf * 16 + g * 4 + r;
          sred[wc * 64 + node] = vs;
          sred[128 + wc * 64 + node] = vd;
        }
      }
  }
  __syncthreads();
  {
    int o = t >> 2, nc = (t & 3) * 16;
    u16* dst = Hbt + ((size_t)(ob * 64 + nb) * 64 + o) * 64 + nc;
#pragma unroll
    for (int c = 0; c < 2; ++c) {
      s16x8 v = *(const s16x8*)(Ct + o * 72 + nc + c * 8);
      *(s16x8*)(dst + c * 8) = v;
    }
  }
  if (t < 64) {
    const float* sred = (const float*)wlo;
    s_srcT[(size_t)ob * NN + nb * 64 + t] = sred[t] + sred[64 + t];
    s_dstT[(size_t)ob * NN + nb * 64 + t] = sred[128 + t] + sred[192 + t];
  }
}

// ---------------------------------------------------------------------------
// Kernel 2b: per-head global max of dst scores (upper bound for fixed-m).
// ---------------------------------------------------------------------------
__global__ __launch_bounds__(512) void gat_dmax(
    const float* __restrict__ s_dstT, float* __restrict__ Mh)
{
  const int w = threadIdx.x >> 6, lane = threadIdx.x & 63;
  const float* p = s_dstT + (size_t)w * NN;
  float m = -INFINITY;
#pragma unroll
  for (int it = 0; it < 16; ++it) {
    f32x4 v = *(const f32x4*)(p + (it * 64 + lane) * 4);
    m = fmaxf(fmaxf(fmaxf(m, v[0]), v[1]), fmaxf(v[2], v[3]));
  }
#pragma unroll
  for (int s = 1; s < 64; s <<= 1) m = fmaxf(m, __shfl_xor(m, s));
  if (lane == 0) Mh[w] = m;
}

// ---------------------------------------------------------------------------
// Kernel 3: flash-GAT. R10's proven shape: block = (head, 64 i-rows), 512
// threads = 8 waves = 4 i-subwaves x 2 j-halves; grid 512 -> 2 blk/CU.
// Double-buffered staging -> ONE barrier per tile. Race-free: a wave's
// reads of buf[p] drain (lgkmcnt) before it reaches barrier(it+1); the
// next write of buf[p] occurs after barrier(it+1). Fixed-m softmax ->
// j-half partials (acc, l) merge by plain addition.
// head = bid&7 keeps each head's 512KB A-slice XCD-pinned in L2.
// ---------------------------------------------------------------------------
__global__ __launch_bounds__(512, 4) void gat_flash(
    const u64* __restrict__ bits, const u16* __restrict__ Hbt,
    const float* __restrict__ s_srcT, const float* __restrict__ s_dstT,
    const float* __restrict__ Mh, float* __restrict__ pout)
{
  __shared__ char shmem[32768];   // u16 Ast[2 jh][2 dbuf][4096] | float accst[4][16][66]
  __shared__ float Lbuf[8][16];
  u16* Ast = (u16*)shmem;

  const int t = threadIdx.x, lane = t & 63, wid = t >> 6;
  const int ws4 = wid & 3, jh = wid >> 2;
  const int bid = blockIdx.x;
  const int h = bid & 7, iblk = bid >> 3;
  const int i_loc = lane & 15, g = lane >> 4, j0 = g * 8;
  const int irow = iblk * 64 + ws4 * 16 + i_loc;

  const float s_i = s_srcT[(size_t)h * NN + irow];
  float m_i = s_i + Mh[h];
  m_i = fmaxf(m_i, 0.2f * m_i);                 // lrelu(s_i + M_h) >= all z
  const float L2E = 1.44269504f;
  const float mL = m_i * L2E;

  const u16* tile0 = Hbt + (size_t)h * 64 * 4096;   // + jt*4096
  const float* dT = s_dstT + (size_t)h * NN;
  const u64* brow = bits + (size_t)irow * 64;

  const int lt = t & 255;
  const int r0 = lt >> 3, colE = (lt & 7) * 8;
  const u16* gsrc0 = tile0 + r0 * 64 + (colE ^ ((r0 & 7) << 3));
  const u16* gsrc1 = tile0 + (32 + r0) * 64 + (colE ^ ((r0 & 7) << 3));
  u16* sgrp = Ast + jh * 8192;
  const int swz = (i_loc & 7) << 4;

  f32x4 acc[4] = {};
  f32x4 lacc = {0.f, 0.f, 0.f, 0.f};

#define QUAD(DV, MBITS, SH, PW0, PW1, LI) do {                        \
    float z0 = s_i + DV[0], z1 = s_i + DV[1];                         \
    float z2 = s_i + DV[2], z3 = s_i + DV[3];                         \
    z0 = fmaxf(z0, 0.2f * z0); z1 = fmaxf(z1, 0.2f * z1);             \
    z2 = fmaxf(z2, 0.2f * z2); z3 = fmaxf(z3, 0.2f * z3);             \
    float e0 = __builtin_amdgcn_exp2f(__builtin_fmaf(z0, L2E, -mL));  \
    float e1 = __builtin_amdgcn_exp2f(__builtin_fmaf(z1, L2E, -mL));  \
    float e2 = __builtin_amdgcn_exp2f(__builtin_fmaf(z2, L2E, -mL));  \
    float e3 = __builtin_amdgcn_exp2f(__builtin_fmaf(z3, L2E, -mL));  \
    e0 = ((MBITS >> (SH + 0)) & 1u) ? e0 : 0.f;                       \
    e1 = ((MBITS >> (SH + 1)) & 1u) ? e1 : 0.f;                       \
    e2 = ((MBITS >> (SH + 2)) & 1u) ? e2 : 0.f;                       \
    e3 = ((MBITS >> (SH + 3)) & 1u) ? e3 : 0.f;                       \
    lacc[LI] += (e0 + e1) + (e2 + e3);                                \
    PW0 = cvt_pk_bf16(e0, e1); PW1 = cvt_pk_bf16(e2, e3);             \
  } while (0)

  const int jtb = jh * 32;
  s16x8 sv0 = *(const s16x8*)(gsrc0 + jtb * 4096);
  s16x8 sv1 = *(const s16x8*)(gsrc1 + jtb * 4096);

  for (int it = 0; it < 32; ++it) {
    const int jt = jtb + it;
    u16* sdst = sgrp + (it & 1) * 4096;

    // stage tile it (loaded last iteration), then prefetch it+1
    *(s16x8*)(sdst + lt * 8) = sv0;
    *(s16x8*)(sdst + 2048 + lt * 8) = sv1;
    if (it < 31) {
      sv0 = *(const s16x8*)(gsrc0 + (jt + 1) * 4096);
      sv1 = *(const s16x8*)(gsrc1 + (jt + 1) * 4096);
    }

    // softmax for tile jt (mask + d loads are L1/L2-hot)
    const u64 am_ = brow[jt];
    const float* dp = dT + jt * 64 + j0;
    f32x4 d0 = *(const f32x4*)(dp);
    f32x4 d1 = *(const f32x4*)(dp + 4);
    f32x4 d2 = *(const f32x4*)(dp + 32);
    f32x4 d3 = *(const f32x4*)(dp + 36);
    const unsigned amlo = (unsigned)(am_ >> j0);
    const unsigned amhi = (unsigned)(am_ >> (32 + j0));
    union { unsigned w_[4]; s16x8 v_; } P0, P1;
    QUAD(d0, amlo, 0, P0.w_[0], P0.w_[1], 0);
    QUAD(d1, amlo, 4, P0.w_[2], P0.w_[3], 1);
    QUAD(d2, amhi, 0, P1.w_[0], P1.w_[1], 2);
    QUAD(d3, amhi, 4, P1.w_[2], P1.w_[3], 3);

    __syncthreads();              // staged writes visible; prev-prev reads done

    const char* lbase = (const char*)sdst;
#pragma unroll
    for (int fb = 0; fb < 4; ++fb) {
      const int rowb = (fb * 16 + i_loc) * 128;
      s16x8 A0 = *(const s16x8*)(lbase + rowb + ((g * 16) ^ swz));
      s16x8 A1 = *(const s16x8*)(lbase + rowb + (((g * 16) + 64) ^ swz));
      acc[fb] = __builtin_amdgcn_mfma_f32_16x16x32_bf16(A0, P0.v_, acc[fb], 0, 0, 0);
      acc[fb] = __builtin_amdgcn_mfma_f32_16x16x32_bf16(A1, P1.v_, acc[fb], 0, 0, 0);
    }
  }
#undef QUAD

  // l for this wave's j-half
  float l_run = (lacc[0] + lacc[1]) + (lacc[2] + lacc[3]);
  l_run += __shfl_xor(l_run, 16);
  l_run += __shfl_xor(l_run, 32);
  if (lane < 16) Lbuf[wid][i_loc] = l_run;

  __syncthreads();     // final tile's ds_reads retired; Lbuf visible
  float* accst = (float*)shmem;  // [4][16][66] = jh==1's 4 i-subwaves
  if (jh == 1) {
    float* ab = accst + (ws4 * 16 + i_loc) * 66;
#pragma unroll
    for (int fb = 0; fb < 4; ++fb)
      *(f32x4*)(ab + fb * 16 + g * 4) = acc[fb];
  }
  __syncthreads();
  if (jh == 0) {
    const float invL = 1.f / (l_run + Lbuf[4 + ws4][i_loc]);
    float* ob = pout + ((size_t)h * NN + irow) * 64;
#pragma unroll
    for (int fb = 0; fb < 4; ++fb) {
      f32x4 v = acc[fb] +
          *(const f32x4*)(accst + (ws4 * 16 + i_loc) * 66 + fb * 16 + g * 4);
      *(f32x4*)(ob + fb * 16 + g * 4) = v * invL;
    }
  }
}

// ---------------------------------------------------------------------------
// Kernel 4: combine 8 per-head partials, apply 1/8 head-mean.
// ---------------------------------------------------------------------------
__global__ __launch_bounds__(256) void gat_combine(
    const float* __restrict__ pout, float* __restrict__ out)
{
  size_t e = (size_t)blockIdx.x * 256 + threadIdx.x;   // f32x4 index
  f32x4 s = {0.f, 0.f, 0.f, 0.f};
#pragma unroll
  for (int h = 0; h < 8; ++h)
    s += ((const f32x4*)pout)[(size_t)h * (NN * 16) + e];
  ((f32x4*)out)[e] = s * 0.125f;
}

extern "C" void kernel_launch(void* const* d_in, const int* in_sizes, int n_in,
                              void* d_out, int out_size, void* d_ws, size_t ws_size,
                              hipStream_t stream)
{
  const float* x = (const float*)d_in[0];
  const void* adj = d_in[1];
  const float* W = (const float*)d_in[2];
  const float* a_src = (const float*)d_in[3];
  const float* a_dst = (const float*)d_in[4];
  float* out = (float*)d_out;

  char* ws = (char*)d_ws;
  float* pout = (float*)ws;                                 // 8 MB [8][4096][64]
  u16* Hbt = (u16*)(ws + 8 * 1024 * 1024);                  // 4 MB [8][64][64][64] bf16 tiled
  float* s_srcT = (float*)(ws + 12 * 1024 * 1024);          // 128 KB [8][4096]
  float* s_dstT = (float*)(ws + 12 * 1024 * 1024 + 128 * 1024);
  float* Mh = (float*)(ws + 12 * 1024 * 1024 + 384 * 1024); // 32 B
  u64* bits = (u64*)(ws + 12 * 1024 * 1024 + 512 * 1024);   // 2 MB

  gat_pack<<<2048, 256, 0, stream>>>(adj, bits);
  gat_gemm1<<<dim3(64, 8), 256, 0, stream>>>(x, W, a_src, a_dst, Hbt, s_srcT, s_dstT);
  gat_dmax<<<1, 512, 0, stream>>>(s_dstT, Mh);
  gat_flash<<<512, 512, 0, stream>>>(bits, Hbt, s_srcT, s_dstT, Mh, pout);
  gat_combine<<<256, 256, 0, stream>>>(pout, out);
}